// Round 8
// baseline (130.956 us; speedup 1.0000x reference)
//
#include <hip/hip_runtime.h>

#define NN 50000
#define NE 800000
#define FIN 128
#define NH 4
#define HD 32
#define FOUT 128   // NH*HD
#define NEG 0.2f
#define NB_SCAN ((NN + 255) / 256)   // 196
#define NB_EDGE ((NE + 255) / 256)   // 3125
#define NB_W    ((256 * FIN + 255) / 256) // 128
#define N_GEMM  (391 * 4)            // 1564 gemm tiles
#define NBKT    98                   // dst>>9 buckets (512 nodes each)
#define CHUNK   4096                 // edges per phase-A block
#define NCHUNK  ((NE + CHUNK - 1) / CHUNK)  // 196
#define GB_GRID (NCHUNK * 9)         // 1764: b%9==0 -> phaseA, else gemm
#define BCAP    12288                // phase-B LDS segment capacity (mean 8163)

typedef __attribute__((ext_vector_type(8))) short bf16x8;
typedef __attribute__((ext_vector_type(4))) float f32x4;

__device__ __forceinline__ ushort f2bf(float f) {
    uint u = __float_as_uint(f);
    u += 0x7FFF + ((u >> 16) & 1);   // round-to-nearest-even
    return (ushort)(u >> 16);
}
__device__ __forceinline__ float blo(uint u) { return __uint_as_float(u << 16); }
__device__ __forceinline__ float bhi(uint u) { return __uint_as_float(u & 0xffff0000u); }

template<int CTRL>
__device__ __forceinline__ float dpp_add(float x) {
    int y = __builtin_amdgcn_update_dpp(0, __float_as_int(x), CTRL, 0xF, 0xF, false);
    return x + __int_as_float(y);
}
#define DPP_QUAD_XOR1 0xB1   // quad_perm [1,0,3,2]
#define DPP_QUAD_XOR2 0x4E   // quad_perm [2,3,0,1]

// ---------------- zero cnt (hipMemsetAsync's fill kernel costs 42us; this is ~2us) ----------------
__global__ __launch_bounds__(256) void zero_k(int4* __restrict__ p, int n4)
{
    int i = blockIdx.x * 256 + threadIdx.x;
    if (i < n4) p[i] = make_int4(0, 0, 0, 0);
}

// ---------------- conv x -> bf16 + dst-degree count + conv W ----------------
__global__ __launch_bounds__(256) void conv_all_k(
    const float* __restrict__ x, ushort* __restrict__ xb,
    const int* __restrict__ dst, int* __restrict__ cnt,
    const float* __restrict__ Wsrc, const float* __restrict__ Wdst,
    ushort* __restrict__ Wt)
{
    const int b = blockIdx.x;
    if (b < NB_EDGE) {
        int i = b * 256 + threadIdx.x;
        if (i >= NE) return;
        atomicAdd(&cnt[dst[i]], 1);
        float4 a = ((const float4*)x)[2 * i];
        float4 c = ((const float4*)x)[2 * i + 1];
        uint4 o;
        o.x = (uint)f2bf(a.x) | ((uint)f2bf(a.y) << 16);
        o.y = (uint)f2bf(a.z) | ((uint)f2bf(a.w) << 16);
        o.z = (uint)f2bf(c.x) | ((uint)f2bf(c.y) << 16);
        o.w = (uint)f2bf(c.z) | ((uint)f2bf(c.w) << 16);
        *(uint4*)&xb[8 * i] = o;
    } else {
        int t = (b - NB_EDGE) * 256 + threadIdx.x;
        if (t >= 256 * FIN) return;
        int n = t >> 7, k = t & 127;
        float v = (n < 128) ? Wsrc[k * 128 + n] : Wdst[k * 128 + (n - 128)];
        Wt[t] = f2bf(v);
    }
}

// ---------------- CSR scan ----------------
__global__ __launch_bounds__(256) void scanA_k(const int* __restrict__ cnt,
                                               int* __restrict__ rowptr, int* __restrict__ bsum)
{
    __shared__ int sh[256];
    int t = threadIdx.x, g = blockIdx.x * 256 + t;
    sh[t] = (g < NN) ? cnt[g] : 0;
    __syncthreads();
    for (int off = 1; off < 256; off <<= 1) {
        int add = (t >= off) ? sh[t - off] : 0;
        __syncthreads();
        sh[t] += add;
        __syncthreads();
    }
    if (g < NN) rowptr[g + 1] = sh[t];
    if (t == 255) bsum[blockIdx.x] = sh[255];
}

// rowptr finalize + bucket_cursor init
__global__ __launch_bounds__(256) void scanC_k(int* __restrict__ rowptr, const int* __restrict__ bsum,
                                               int* __restrict__ bucket_cursor)
{
    __shared__ int red[256];
    const int t = threadIdx.x;
    int part = 0;
    for (int j = t; j < blockIdx.x; j += 256) part += bsum[j];
    red[t] = part;
    __syncthreads();
    for (int off = 128; off; off >>= 1) {
        if (t < off) red[t] += red[t + off];
        __syncthreads();
    }
    const int prefix = red[0];
    const int g = blockIdx.x * 256 + t;
    if (g < NN) {
        int v = rowptr[g + 1] + prefix;
        rowptr[g + 1] = v;
        if (((g + 1) & 511) == 0 && (g + 1) < NN)
            bucket_cursor[(g + 1) >> 9] = v;   // bucket base = rowptr[512b]
    }
    if (g == 0) { rowptr[0] = 0; bucket_cursor[0] = 0; }
}

// ---------------- FUSED: MFMA GEMM tiles + phase-A edge bucketing ----------------
__global__ __launch_bounds__(256) void gemm_binA_k(
    const ushort* __restrict__ xb, const ushort* __restrict__ Wt,
    const float* __restrict__ bsrc, const float* __restrict__ bdst,
    ushort* __restrict__ fsfd,
    const int* __restrict__ dst, const int* __restrict__ src,
    int* __restrict__ bucket_cursor, uint* __restrict__ ebuf)
{
    __shared__ ushort As[128 * 128];
    __shared__ ushort Bs[64 * 128];
    __shared__ int hist[NBKT];
    __shared__ int base[NBKT];
    const int b = blockIdx.x;
    const int tid = threadIdx.x;

    if (b % 9 == 0) {
        // ---- phase A: bucketize 4096 edges ----
        const int chunk = b / 9;
        const int e0 = chunk * CHUNK;
        int d[16], s[16];
        for (int t = tid; t < NBKT; t += 256) hist[t] = 0;
        __syncthreads();
        #pragma unroll
        for (int k = 0; k < 16; ++k) {
            const int e = e0 + k * 256 + tid;
            if (e < NE) {
                d[k] = dst[e];
                s[k] = src[e];
                atomicAdd(&hist[d[k] >> 9], 1);
            } else d[k] = -1;
        }
        __syncthreads();
        for (int t = tid; t < NBKT; t += 256) {
            base[t] = atomicAdd(&bucket_cursor[t], hist[t]);
            hist[t] = 0;
        }
        __syncthreads();
        #pragma unroll
        for (int k = 0; k < 16; ++k) {
            if (d[k] >= 0) {
                const int bkt = d[k] >> 9;
                const int off = atomicAdd(&hist[bkt], 1);
                ebuf[base[bkt] + off] = ((uint)d[k] << 16) | (uint)s[k];
            }
        }
        return;
    }

    // ---- gemm role ----
    const int g = b - b / 9 - 1;
    if (g >= N_GEMM) return;
    const int bm = (g >> 2) * 128;
    const int bn = (g & 3) * 64;

    for (int q = tid; q < 128 * 16; q += 256) {
        int r = q >> 4, c16 = q & 15;
        int row = bm + r;
        uint4 v = make_uint4(0u, 0u, 0u, 0u);
        if (row < NN) v = *(const uint4*)&xb[row * FIN + c16 * 8];
        int off = r * 256 + ((c16 * 16) ^ ((r & 7) << 4));
        *(uint4*)((char*)As + off) = v;
    }
    for (int q = tid; q < 64 * 16; q += 256) {
        int r = q >> 4, c16 = q & 15;
        uint4 v = *(const uint4*)&Wt[(bn + r) * FIN + c16 * 8];
        int off = r * 256 + ((c16 * 16) ^ ((r & 7) << 4));
        *(uint4*)((char*)Bs + off) = v;
    }
    __syncthreads();

    const int wid = tid >> 6, lane = tid & 63;
    const int wr = (wid >> 1) * 64, wc = (wid & 1) * 32;
    const int lrow = lane & 15;
    const int lk = (lane >> 4) * 16;

    f32x4 acc[4][2] = {};
    #pragma unroll
    for (int kk = 0; kk < 4; ++kk) {
        bf16x8 a[4], bb[2];
        #pragma unroll
        for (int m = 0; m < 4; ++m) {
            int r = wr + m * 16 + lrow;
            int off = r * 256 + ((kk * 64 + lk) ^ ((r & 7) << 4));
            a[m] = *(bf16x8*)((char*)As + off);
        }
        #pragma unroll
        for (int n = 0; n < 2; ++n) {
            int r = wc + n * 16 + lrow;
            int off = r * 256 + ((kk * 64 + lk) ^ ((r & 7) << 4));
            bb[n] = *(bf16x8*)((char*)Bs + off);
        }
        #pragma unroll
        for (int m = 0; m < 4; ++m)
            #pragma unroll
            for (int n = 0; n < 2; ++n)
                acc[m][n] = __builtin_amdgcn_mfma_f32_16x16x32_bf16(a[m], bb[n], acc[m][n], 0, 0, 0);
    }

    #pragma unroll
    for (int m = 0; m < 4; ++m) {
        #pragma unroll
        for (int n = 0; n < 2; ++n) {
            int gcol = bn + wc + n * 16 + (lane & 15);
            float bias = (gcol < 128) ? bsrc[gcol] : bdst[gcol - 128];
            #pragma unroll
            for (int r = 0; r < 4; ++r) {
                int grow = bm + wr + m * 16 + (lane >> 4) * 4 + r;
                if (grow < NN)
                    fsfd[(size_t)grow * 256 + gcol] = f2bf(acc[m][n][r] + bias);
            }
        }
    }
}

// ---------------- phase B: per-bucket LDS scatter, coalesced nbr write ----------------
__global__ __launch_bounds__(256) void binB_k(
    const uint* __restrict__ ebuf, const int* __restrict__ rowptr,
    ushort* __restrict__ nbr)
{
    __shared__ int cur[512];
    __shared__ ushort buf[BCAP];
    const int b = blockIdx.x;
    const int tid = threadIdx.x;
    const int node0 = b << 9;
    const int node1 = (node0 + 512 < NN) ? node0 + 512 : NN;
    const int segbase = rowptr[node0];
    const int segend  = rowptr[node1];
    const int seglen  = segend - segbase;

    for (int i = tid; i < node1 - node0; i += 256)
        cur[i] = rowptr[node0 + i] - segbase;
    __syncthreads();

    if (seglen <= BCAP) {
        for (int i = segbase + tid; i < segend; i += 256) {
            const uint e = ebuf[i];
            const int d = (int)(e >> 16);
            const int p = atomicAdd(&cur[d - node0], 1);
            buf[p] = (ushort)(e & 0xffffu);
        }
        __syncthreads();
        for (int i = tid; i < seglen; i += 256)
            nbr[segbase + i] = buf[i];
    } else {
        if (tid == 0) {
            for (int i = segbase; i < segend; ++i) {
                const uint e = ebuf[i];
                const int d = (int)(e >> 16);
                nbr[segbase + cur[d - node0]++] = (ushort)(e & 0xffffu);
            }
        }
    }
}

// ---------------- Fused per-node GAT kernel ----------------
// One wave per node. ql = lane&15 owns elems {8ql..8ql+7}; quarter-waves (lane>>4)
// process 4 edges concurrently. Head = ql>>2; score reduce = 2 quad-DPP adds.
__global__ __launch_bounds__(256) void gat_node_k(
    const ushort* __restrict__ fsfd, const float* __restrict__ attn,
    const int* __restrict__ rowptr, const ushort* __restrict__ nbr,
    float* __restrict__ out)
{
    const int node = blockIdx.x * 4 + (threadIdx.x >> 6);
    const int lane = threadIdx.x & 63;
    const int ql = lane & 15;
    const int q  = lane >> 4;

    const uint4 ufd = *(const uint4*)&fsfd[(size_t)node * 256 + 128 + 8 * ql];
    float fd[8];
    fd[0] = blo(ufd.x); fd[1] = bhi(ufd.x);
    fd[2] = blo(ufd.y); fd[3] = bhi(ufd.y);
    fd[4] = blo(ufd.z); fd[5] = bhi(ufd.z);
    fd[6] = blo(ufd.w); fd[7] = bhi(ufd.w);
    const float4 av0 = *(const float4*)&attn[8 * ql];
    const float4 av1 = *(const float4*)&attn[8 * ql + 4];
    const float av[8] = {av0.x, av0.y, av0.z, av0.w, av1.x, av1.y, av1.z, av1.w};

    const int beg = rowptr[node];
    const int end = rowptr[node + 1];

    float den = 0.f;
    float acc[8] = {0.f, 0.f, 0.f, 0.f, 0.f, 0.f, 0.f, 0.f};

    for (int i = beg; i < end; i += 8) {
        #pragma unroll
        for (int j = 0; j < 2; ++j) {
            const int idx = i + 4 * j + q;
            const bool valid = idx < end;
            const int s = nbr[valid ? idx : end - 1];
            const uint4 u = *(const uint4*)&fsfd[(size_t)s * 256 + 8 * ql];
            float f[8];
            f[0] = blo(u.x); f[1] = bhi(u.x);
            f[2] = blo(u.y); f[3] = bhi(u.y);
            f[4] = blo(u.z); f[5] = bhi(u.z);
            f[6] = blo(u.w); f[7] = bhi(u.w);
            float sc = 0.f;
            #pragma unroll
            for (int e2 = 0; e2 < 8; ++e2) {
                float v = f[e2] + fd[e2];
                v = fmaxf(v, NEG * v);
                sc = fmaf(v, av[e2], sc);
            }
            // 4-lane quad (one head) butterfly sum, broadcast
            sc = dpp_add<DPP_QUAD_XOR1>(sc);
            sc = dpp_add<DPP_QUAD_XOR2>(sc);
            float ex = __expf(sc);
            ex = valid ? ex : 0.f;
            den += ex;
            #pragma unroll
            for (int e2 = 0; e2 < 8; ++e2)
                acc[e2] = fmaf(ex, f[e2], acc[e2]);
        }
    }

    // merge the 4 quarter-wave accumulators (once per node)
    den += __shfl_xor(den, 16, 64);
    den += __shfl_xor(den, 32, 64);
    #pragma unroll
    for (int e2 = 0; e2 < 8; ++e2) {
        acc[e2] += __shfl_xor(acc[e2], 16, 64);
        acc[e2] += __shfl_xor(acc[e2], 32, 64);
    }

    if (q == 0) {
        const float inv = (den > 0.f) ? 1.f / den : 0.f;
        float4 o0, o1;
        o0.x = fmaxf(acc[0] * inv, 0.f);
        o0.y = fmaxf(acc[1] * inv, 0.f);
        o0.z = fmaxf(acc[2] * inv, 0.f);
        o0.w = fmaxf(acc[3] * inv, 0.f);
        o1.x = fmaxf(acc[4] * inv, 0.f);
        o1.y = fmaxf(acc[5] * inv, 0.f);
        o1.z = fmaxf(acc[6] * inv, 0.f);
        o1.w = fmaxf(acc[7] * inv, 0.f);
        *(float4*)&out[(size_t)node * FOUT + 8 * ql] = o0;
        *(float4*)&out[(size_t)node * FOUT + 8 * ql + 4] = o1;
    }
}

extern "C" void kernel_launch(void* const* d_in, const int* in_sizes, int n_in,
                              void* d_out, int out_size, void* d_ws, size_t ws_size,
                              hipStream_t stream)
{
    const float* x    = (const float*)d_in[0];
    const int*   src  = (const int*)d_in[1];
    const int*   dst  = (const int*)d_in[2];
    const float* Wsrc = (const float*)d_in[3];
    const float* bsrc = (const float*)d_in[4];
    const float* Wdst = (const float*)d_in[5];
    const float* bdst = (const float*)d_in[6];
    const float* attn = (const float*)d_in[7];
    float* out = (float*)d_out;

    ushort* xb   = (ushort*)d_ws;                         // NN*128 bf16
    ushort* Wt   = xb + (size_t)NN * FIN;                 // 256*128 bf16
    ushort* fsfd = Wt + 256 * FIN;                        // NN*256 bf16
    int* cnt     = (int*)(fsfd + (size_t)NN * 256);       // NN
    int* rowptr  = cnt + NN;                              // NN+1
    int* bsum    = rowptr + NN + 1;                       // NB_SCAN
    int* bkcur   = bsum + 256;                            // NBKT
    uint* ebuf   = (uint*)(bkcur + 128);                  // NE packed (d<<16)|s
    ushort* nbr  = (ushort*)(ebuf + NE);                  // NE u16

    zero_k<<<(NN / 4 + 255) / 256, 256, 0, stream>>>((int4*)cnt, NN / 4);
    conv_all_k<<<NB_EDGE + NB_W, 256, 0, stream>>>(x, xb, dst, cnt, Wsrc, Wdst, Wt);
    scanA_k<<<NB_SCAN, 256, 0, stream>>>(cnt, rowptr, bsum);
    scanC_k<<<NB_SCAN, 256, 0, stream>>>(rowptr, bsum, bkcur);
    gemm_binA_k<<<GB_GRID, 256, 0, stream>>>(xb, Wt, bsrc, bdst, fsfd,
                                             dst, src, bkcur, ebuf);
    binB_k<<<NBKT, 256, 0, stream>>>(ebuf, rowptr, nbr);
    gat_node_k<<<(NN + 3) / 4, 256, 0, stream>>>(fsfd, attn, rowptr, nbr, out);
}

// Round 10
// 126.830 us; speedup vs baseline: 1.0325x; 1.0325x over previous
//
#include <hip/hip_runtime.h>
#include <hip/hip_fp16.h>

#define NN 50000
#define NE 800000
#define FIN 128
#define NH 4
#define HD 32
#define FOUT 128   // NH*HD
#define NEG 0.2f
#define NB_SCAN ((NN + 255) / 256)   // 196
#define NB_EDGE ((NE + 255) / 256)   // 3125
#define NB_W    ((256 * FIN + 255) / 256) // 128
#define N_GEMM  (391 * 4)            // 1564 gemm tiles
#define NBKT    98                   // dst>>9 buckets (512 nodes each)
#define CHUNK   4096                 // edges per phase-A block
#define NCHUNK  ((NE + CHUNK - 1) / CHUNK)  // 196
#define GB_GRID (NCHUNK * 9)         // 1764: b%9==0 -> phaseA, else gemm
#define BCAP    12288                // phase-B LDS segment capacity (mean 8163)

typedef __attribute__((ext_vector_type(8))) short bf16x8;
typedef __attribute__((ext_vector_type(4))) float f32x4;

__device__ __forceinline__ ushort f2bf(float f) {
    uint u = __float_as_uint(f);
    u += 0x7FFF + ((u >> 16) & 1);   // round-to-nearest-even
    return (ushort)(u >> 16);
}

template<int CTRL>
__device__ __forceinline__ float dpp_add(float x) {
    int y = __builtin_amdgcn_update_dpp(0, __float_as_int(x), CTRL, 0xF, 0xF, false);
    return x + __int_as_float(y);
}
#define DPP_QUAD_XOR1 0xB1   // quad_perm [1,0,3,2]
#define DPP_QUAD_XOR2 0x4E   // quad_perm [2,3,0,1]

__device__ __forceinline__ __half2 u2h(uint u) { return __builtin_bit_cast(__half2, u); }
__device__ __forceinline__ uint h2u(__half2 h) { return __builtin_bit_cast(uint, h); }

// ROCm 7.2 hip_fp16.h lacks __hmax2 — emit v_pk_max_f16 directly
__device__ __forceinline__ __half2 hmax2(__half2 a, __half2 b) {
    uint r, ua = h2u(a), ub = h2u(b);
    asm("v_pk_max_f16 %0, %1, %2" : "=v"(r) : "v"(ua), "v"(ub));
    return u2h(r);
}

// ---------------- zero cnt + precompute attn in f16 ----------------
__global__ __launch_bounds__(256) void zero_k(int4* __restrict__ p, int n4,
                                              const float* __restrict__ attn,
                                              __half* __restrict__ attn_h)
{
    int i = blockIdx.x * 256 + threadIdx.x;
    if (i < n4) p[i] = make_int4(0, 0, 0, 0);
    if (blockIdx.x == 0 && threadIdx.x < FOUT)
        attn_h[threadIdx.x] = __float2half(attn[threadIdx.x]);
}

// ---------------- conv x -> bf16 + dst-degree count + conv W ----------------
__global__ __launch_bounds__(256) void conv_all_k(
    const float* __restrict__ x, ushort* __restrict__ xb,
    const int* __restrict__ dst, int* __restrict__ cnt,
    const float* __restrict__ Wsrc, const float* __restrict__ Wdst,
    ushort* __restrict__ Wt)
{
    const int b = blockIdx.x;
    if (b < NB_EDGE) {
        int i = b * 256 + threadIdx.x;
        if (i >= NE) return;
        atomicAdd(&cnt[dst[i]], 1);
        float4 a = ((const float4*)x)[2 * i];
        float4 c = ((const float4*)x)[2 * i + 1];
        uint4 o;
        o.x = (uint)f2bf(a.x) | ((uint)f2bf(a.y) << 16);
        o.y = (uint)f2bf(a.z) | ((uint)f2bf(a.w) << 16);
        o.z = (uint)f2bf(c.x) | ((uint)f2bf(c.y) << 16);
        o.w = (uint)f2bf(c.z) | ((uint)f2bf(c.w) << 16);
        *(uint4*)&xb[8 * i] = o;
    } else {
        int t = (b - NB_EDGE) * 256 + threadIdx.x;
        if (t >= 256 * FIN) return;
        int n = t >> 7, k = t & 127;
        float v = (n < 128) ? Wsrc[k * 128 + n] : Wdst[k * 128 + (n - 128)];
        Wt[t] = f2bf(v);
    }
}

// ---------------- CSR scan ----------------
__global__ __launch_bounds__(256) void scanA_k(const int* __restrict__ cnt,
                                               int* __restrict__ rowptr, int* __restrict__ bsum)
{
    __shared__ int sh[256];
    int t = threadIdx.x, g = blockIdx.x * 256 + t;
    sh[t] = (g < NN) ? cnt[g] : 0;
    __syncthreads();
    for (int off = 1; off < 256; off <<= 1) {
        int add = (t >= off) ? sh[t - off] : 0;
        __syncthreads();
        sh[t] += add;
        __syncthreads();
    }
    if (g < NN) rowptr[g + 1] = sh[t];
    if (t == 255) bsum[blockIdx.x] = sh[255];
}

// rowptr finalize + bucket_cursor init
__global__ __launch_bounds__(256) void scanC_k(int* __restrict__ rowptr, const int* __restrict__ bsum,
                                               int* __restrict__ bucket_cursor)
{
    __shared__ int red[256];
    const int t = threadIdx.x;
    int part = 0;
    for (int j = t; j < blockIdx.x; j += 256) part += bsum[j];
    red[t] = part;
    __syncthreads();
    for (int off = 128; off; off >>= 1) {
        if (t < off) red[t] += red[t + off];
        __syncthreads();
    }
    const int prefix = red[0];
    const int g = blockIdx.x * 256 + t;
    if (g < NN) {
        int v = rowptr[g + 1] + prefix;
        rowptr[g + 1] = v;
        if (((g + 1) & 511) == 0 && (g + 1) < NN)
            bucket_cursor[(g + 1) >> 9] = v;   // bucket base = rowptr[512b]
    }
    if (g == 0) { rowptr[0] = 0; bucket_cursor[0] = 0; }
}

// ---------------- FUSED: MFMA GEMM tiles + phase-A edge bucketing ----------------
__global__ __launch_bounds__(256) void gemm_binA_k(
    const ushort* __restrict__ xb, const ushort* __restrict__ Wt,
    const float* __restrict__ bsrc, const float* __restrict__ bdst,
    __half* __restrict__ fsfd,
    const int* __restrict__ dst, const int* __restrict__ src,
    int* __restrict__ bucket_cursor, uint* __restrict__ ebuf)
{
    __shared__ ushort As[128 * 128];
    __shared__ ushort Bs[64 * 128];
    __shared__ int hist[NBKT];
    __shared__ int base[NBKT];
    const int b = blockIdx.x;
    const int tid = threadIdx.x;

    if (b % 9 == 0) {
        // ---- phase A: bucketize 4096 edges ----
        const int chunk = b / 9;
        const int e0 = chunk * CHUNK;
        int d[16], s[16];
        for (int t = tid; t < NBKT; t += 256) hist[t] = 0;
        __syncthreads();
        #pragma unroll
        for (int k = 0; k < 16; ++k) {
            const int e = e0 + k * 256 + tid;
            if (e < NE) {
                d[k] = dst[e];
                s[k] = src[e];
                atomicAdd(&hist[d[k] >> 9], 1);
            } else d[k] = -1;
        }
        __syncthreads();
        for (int t = tid; t < NBKT; t += 256) {
            base[t] = atomicAdd(&bucket_cursor[t], hist[t]);
            hist[t] = 0;
        }
        __syncthreads();
        #pragma unroll
        for (int k = 0; k < 16; ++k) {
            if (d[k] >= 0) {
                const int bkt = d[k] >> 9;
                const int off = atomicAdd(&hist[bkt], 1);
                ebuf[base[bkt] + off] = ((uint)d[k] << 16) | (uint)s[k];
            }
        }
        return;
    }

    // ---- gemm role ----
    const int g = b - b / 9 - 1;
    if (g >= N_GEMM) return;
    const int bm = (g >> 2) * 128;
    const int bn = (g & 3) * 64;

    for (int q = tid; q < 128 * 16; q += 256) {
        int r = q >> 4, c16 = q & 15;
        int row = bm + r;
        uint4 v = make_uint4(0u, 0u, 0u, 0u);
        if (row < NN) v = *(const uint4*)&xb[row * FIN + c16 * 8];
        int off = r * 256 + ((c16 * 16) ^ ((r & 7) << 4));
        *(uint4*)((char*)As + off) = v;
    }
    for (int q = tid; q < 64 * 16; q += 256) {
        int r = q >> 4, c16 = q & 15;
        uint4 v = *(const uint4*)&Wt[(bn + r) * FIN + c16 * 8];
        int off = r * 256 + ((c16 * 16) ^ ((r & 7) << 4));
        *(uint4*)((char*)Bs + off) = v;
    }
    __syncthreads();

    const int wid = tid >> 6, lane = tid & 63;
    const int wr = (wid >> 1) * 64, wc = (wid & 1) * 32;
    const int lrow = lane & 15;
    const int lk = (lane >> 4) * 16;

    f32x4 acc[4][2] = {};
    #pragma unroll
    for (int kk = 0; kk < 4; ++kk) {
        bf16x8 a[4], bb[2];
        #pragma unroll
        for (int m = 0; m < 4; ++m) {
            int r = wr + m * 16 + lrow;
            int off = r * 256 + ((kk * 64 + lk) ^ ((r & 7) << 4));
            a[m] = *(bf16x8*)((char*)As + off);
        }
        #pragma unroll
        for (int n = 0; n < 2; ++n) {
            int r = wc + n * 16 + lrow;
            int off = r * 256 + ((kk * 64 + lk) ^ ((r & 7) << 4));
            bb[n] = *(bf16x8*)((char*)Bs + off);
        }
        #pragma unroll
        for (int m = 0; m < 4; ++m)
            #pragma unroll
            for (int n = 0; n < 2; ++n)
                acc[m][n] = __builtin_amdgcn_mfma_f32_16x16x32_bf16(a[m], bb[n], acc[m][n], 0, 0, 0);
    }

    #pragma unroll
    for (int m = 0; m < 4; ++m) {
        #pragma unroll
        for (int n = 0; n < 2; ++n) {
            int gcol = bn + wc + n * 16 + (lane & 15);
            float bias = (gcol < 128) ? bsrc[gcol] : bdst[gcol - 128];
            #pragma unroll
            for (int r = 0; r < 4; ++r) {
                int grow = bm + wr + m * 16 + (lane >> 4) * 4 + r;
                if (grow < NN)
                    fsfd[(size_t)grow * 256 + gcol] = __float2half(acc[m][n][r] + bias);
            }
        }
    }
}

// ---------------- phase B: per-bucket LDS scatter, coalesced nbr write ----------------
__global__ __launch_bounds__(256) void binB_k(
    const uint* __restrict__ ebuf, const int* __restrict__ rowptr,
    ushort* __restrict__ nbr)
{
    __shared__ int cur[512];
    __shared__ ushort buf[BCAP];
    const int b = blockIdx.x;
    const int tid = threadIdx.x;
    const int node0 = b << 9;
    const int node1 = (node0 + 512 < NN) ? node0 + 512 : NN;
    const int segbase = rowptr[node0];
    const int segend  = rowptr[node1];
    const int seglen  = segend - segbase;

    for (int i = tid; i < node1 - node0; i += 256)
        cur[i] = rowptr[node0 + i] - segbase;
    __syncthreads();

    if (seglen <= BCAP) {
        for (int i = segbase + tid; i < segend; i += 256) {
            const uint e = ebuf[i];
            const int d = (int)(e >> 16);
            const int p = atomicAdd(&cur[d - node0], 1);
            buf[p] = (ushort)(e & 0xffffu);
        }
        __syncthreads();
        for (int i = tid; i < seglen; i += 256)
            nbr[segbase + i] = buf[i];
    } else {
        if (tid == 0) {
            for (int i = segbase; i < segend; ++i) {
                const uint e = ebuf[i];
                const int d = (int)(e >> 16);
                nbr[segbase + cur[d - node0]++] = (ushort)(e & 0xffffu);
            }
        }
    }
}

// ---------------- Fused per-node GAT kernel (packed f16 math) ----------------
// One wave per node. ql = lane&15 owns elems {8ql..8ql+7} (4 half2); quarter-waves
// process 4 edges concurrently. Head = ql>>2; score reduce = 2 quad-DPP adds.
__global__ __launch_bounds__(256) void gat_node_k(
    const __half* __restrict__ fsfd, const __half* __restrict__ attn_h,
    const int* __restrict__ rowptr, const ushort* __restrict__ nbr,
    float* __restrict__ out)
{
    const int node = blockIdx.x * 4 + (threadIdx.x >> 6);
    const int lane = threadIdx.x & 63;
    const int ql = lane & 15;
    const int q  = lane >> 4;

    const uint4 ufd = *(const uint4*)&fsfd[(size_t)node * 256 + 128 + 8 * ql];
    const __half2 fd0 = u2h(ufd.x), fd1 = u2h(ufd.y), fd2 = u2h(ufd.z), fd3 = u2h(ufd.w);
    const uint4 uav = *(const uint4*)&attn_h[8 * ql];
    const __half2 av0 = u2h(uav.x), av1 = u2h(uav.y), av2 = u2h(uav.z), av3 = u2h(uav.w);
    const __half2 k02 = __float2half2_rn(NEG);

    const int beg = rowptr[node];
    const int end = rowptr[node + 1];

    float den = 0.f;
    __half2 acc0 = u2h(0), acc1 = u2h(0), acc2 = u2h(0), acc3 = u2h(0);

    for (int i = beg; i < end; i += 8) {
        #pragma unroll
        for (int j = 0; j < 2; ++j) {
            const int idx = i + 4 * j + q;
            const bool valid = idx < end;
            const int s = nbr[valid ? idx : end - 1];
            const uint4 u = *(const uint4*)&fsfd[(size_t)s * 256 + 8 * ql];
            const __half2 f0 = u2h(u.x), f1 = u2h(u.y), f2 = u2h(u.z), f3 = u2h(u.w);
            // v = lrelu(f + fd) ; score = dot(v, a)  — all packed
            __half2 v0 = __hadd2(f0, fd0), v1 = __hadd2(f1, fd1);
            __half2 v2 = __hadd2(f2, fd2), v3 = __hadd2(f3, fd3);
            v0 = hmax2(v0, __hmul2(v0, k02));
            v1 = hmax2(v1, __hmul2(v1, k02));
            v2 = hmax2(v2, __hmul2(v2, k02));
            v3 = hmax2(v3, __hmul2(v3, k02));
            __half2 sch = __hmul2(v0, av0);
            sch = __hfma2(v1, av1, sch);
            sch = __hfma2(v2, av2, sch);
            sch = __hfma2(v3, av3, sch);
            float sc = __low2float(sch) + __high2float(sch);
            // 4-lane quad (one head) butterfly sum, broadcast
            sc = dpp_add<DPP_QUAD_XOR1>(sc);
            sc = dpp_add<DPP_QUAD_XOR2>(sc);
            float ex = __expf(sc);
            ex = valid ? ex : 0.f;
            den += ex;
            const __half2 exh = __float2half2_rn(ex);
            acc0 = __hfma2(exh, f0, acc0);
            acc1 = __hfma2(exh, f1, acc1);
            acc2 = __hfma2(exh, f2, acc2);
            acc3 = __hfma2(exh, f3, acc3);
        }
    }

    // merge the 4 quarter-wave accumulators (once per node)
    den += __shfl_xor(den, 16, 64);
    den += __shfl_xor(den, 32, 64);
    uint ua0 = h2u(acc0), ua1 = h2u(acc1), ua2 = h2u(acc2), ua3 = h2u(acc3);
    ua0 = h2u(__hadd2(u2h(ua0), u2h((uint)__shfl_xor((int)ua0, 16, 64))));
    ua1 = h2u(__hadd2(u2h(ua1), u2h((uint)__shfl_xor((int)ua1, 16, 64))));
    ua2 = h2u(__hadd2(u2h(ua2), u2h((uint)__shfl_xor((int)ua2, 16, 64))));
    ua3 = h2u(__hadd2(u2h(ua3), u2h((uint)__shfl_xor((int)ua3, 16, 64))));
    ua0 = h2u(__hadd2(u2h(ua0), u2h((uint)__shfl_xor((int)ua0, 32, 64))));
    ua1 = h2u(__hadd2(u2h(ua1), u2h((uint)__shfl_xor((int)ua1, 32, 64))));
    ua2 = h2u(__hadd2(u2h(ua2), u2h((uint)__shfl_xor((int)ua2, 32, 64))));
    ua3 = h2u(__hadd2(u2h(ua3), u2h((uint)__shfl_xor((int)ua3, 32, 64))));

    if (q == 0) {
        const float inv = (den > 0.f) ? 1.f / den : 0.f;
        float4 o0, o1;
        o0.x = fmaxf(__low2float(u2h(ua0))  * inv, 0.f);
        o0.y = fmaxf(__high2float(u2h(ua0)) * inv, 0.f);
        o0.z = fmaxf(__low2float(u2h(ua1))  * inv, 0.f);
        o0.w = fmaxf(__high2float(u2h(ua1)) * inv, 0.f);
        o1.x = fmaxf(__low2float(u2h(ua2))  * inv, 0.f);
        o1.y = fmaxf(__high2float(u2h(ua2)) * inv, 0.f);
        o1.z = fmaxf(__low2float(u2h(ua3))  * inv, 0.f);
        o1.w = fmaxf(__high2float(u2h(ua3)) * inv, 0.f);
        *(float4*)&out[(size_t)node * FOUT + 8 * ql] = o0;
        *(float4*)&out[(size_t)node * FOUT + 8 * ql + 4] = o1;
    }
}

extern "C" void kernel_launch(void* const* d_in, const int* in_sizes, int n_in,
                              void* d_out, int out_size, void* d_ws, size_t ws_size,
                              hipStream_t stream)
{
    const float* x    = (const float*)d_in[0];
    const int*   src  = (const int*)d_in[1];
    const int*   dst  = (const int*)d_in[2];
    const float* Wsrc = (const float*)d_in[3];
    const float* bsrc = (const float*)d_in[4];
    const float* Wdst = (const float*)d_in[5];
    const float* bdst = (const float*)d_in[6];
    const float* attn = (const float*)d_in[7];
    float* out = (float*)d_out;

    ushort* xb   = (ushort*)d_ws;                         // NN*128 bf16
    ushort* Wt   = xb + (size_t)NN * FIN;                 // 256*128 bf16
    __half* fsfd = (__half*)(Wt + 256 * FIN);             // NN*256 f16
    int* cnt     = (int*)(fsfd + (size_t)NN * 256);       // NN
    int* rowptr  = cnt + NN;                              // NN+1
    int* bsum    = rowptr + NN + 1;                       // NB_SCAN
    int* bkcur   = bsum + 256;                            // NBKT
    uint* ebuf   = (uint*)(bkcur + 128);                  // NE packed (d<<16)|s
    ushort* nbr  = (ushort*)(ebuf + NE);                  // NE u16
    __half* attn_h = (__half*)(nbr + NE);                 // 128 f16

    zero_k<<<(NN / 4 + 255) / 256, 256, 0, stream>>>((int4*)cnt, NN / 4, attn, attn_h);
    conv_all_k<<<NB_EDGE + NB_W, 256, 0, stream>>>(x, xb, dst, cnt, Wsrc, Wdst, Wt);
    scanA_k<<<NB_SCAN, 256, 0, stream>>>(cnt, rowptr, bsum);
    scanC_k<<<NB_SCAN, 256, 0, stream>>>(rowptr, bsum, bkcur);
    gemm_binA_k<<<GB_GRID, 256, 0, stream>>>(xb, Wt, bsrc, bdst, fsfd,
                                             dst, src, bkcur, ebuf);
    binB_k<<<NBKT, 256, 0, stream>>>(ebuf, rowptr, nbr);
    gat_node_k<<<(NN + 3) / 4, 256, 0, stream>>>(fsfd, attn_h, rowptr, nbr, out);
}

// Round 11
// 102.749 us; speedup vs baseline: 1.2745x; 1.2344x over previous
//
#include <hip/hip_runtime.h>
#include <hip/hip_fp16.h>

#define NN 50000
#define NE 800000
#define FIN 128
#define NH 4
#define HD 32
#define FOUT 128   // NH*HD
#define NEG 0.2f
#define NB_EDGE ((NE + 255) / 256)   // 3125
#define NB_W    ((256 * FIN + 255) / 256) // 128
#define N_GEMM  (391 * 4)            // 1564 gemm tiles
#define NBKT    98                   // dst>>9 buckets (512 nodes each)
#define CHUNK   4096                 // edges per hist/scatter chunk
#define NCHUNK  ((NE + CHUNK - 1) / CHUNK)  // 196
#define BCAP    12288                // binB LDS segment capacity (mean 8163, max ~8600)

typedef __attribute__((ext_vector_type(8))) short bf16x8;
typedef __attribute__((ext_vector_type(4))) float f32x4;

__device__ __forceinline__ ushort f2bf(float f) {
    uint u = __float_as_uint(f);
    u += 0x7FFF + ((u >> 16) & 1);   // round-to-nearest-even
    return (ushort)(u >> 16);
}

template<int CTRL>
__device__ __forceinline__ float dpp_add(float x) {
    int y = __builtin_amdgcn_update_dpp(0, __float_as_int(x), CTRL, 0xF, 0xF, false);
    return x + __int_as_float(y);
}
#define DPP_QUAD_XOR1 0xB1   // quad_perm [1,0,3,2]
#define DPP_QUAD_XOR2 0x4E   // quad_perm [2,3,0,1]

__device__ __forceinline__ __half2 u2h(uint u) { return __builtin_bit_cast(__half2, u); }
__device__ __forceinline__ uint h2u(__half2 h) { return __builtin_bit_cast(uint, h); }

// ROCm 7.2 hip_fp16.h lacks __hmax2 — emit v_pk_max_f16 directly
__device__ __forceinline__ __half2 hmax2(__half2 a, __half2 b) {
    uint r, ua = h2u(a), ub = h2u(b);
    asm("v_pk_max_f16 %0, %1, %2" : "=v"(r) : "v"(ua), "v"(ub));
    return u2h(r);
}

// ---------------- conv x -> bf16 + conv W (NO atomics — they cost 30us of line-granular HBM writes) ----------------
__global__ __launch_bounds__(256) void conv_all_k(
    const float* __restrict__ x, ushort* __restrict__ xb,
    const float* __restrict__ Wsrc, const float* __restrict__ Wdst,
    ushort* __restrict__ Wt)
{
    const int b = blockIdx.x;
    if (b < NB_EDGE) {
        int i = b * 256 + threadIdx.x;
        if (i >= NE) return;
        float4 a = ((const float4*)x)[2 * i];
        float4 c = ((const float4*)x)[2 * i + 1];
        uint4 o;
        o.x = (uint)f2bf(a.x) | ((uint)f2bf(a.y) << 16);
        o.y = (uint)f2bf(a.z) | ((uint)f2bf(a.w) << 16);
        o.z = (uint)f2bf(c.x) | ((uint)f2bf(c.y) << 16);
        o.w = (uint)f2bf(c.z) | ((uint)f2bf(c.w) << 16);
        *(uint4*)&xb[8 * i] = o;
    } else {
        int t = (b - NB_EDGE) * 256 + threadIdx.x;
        if (t >= 256 * FIN) return;
        int n = t >> 7, k = t & 127;
        float v = (n < 128) ? Wsrc[k * 128 + n] : Wdst[k * 128 + (n - 128)];
        Wt[t] = f2bf(v);
    }
}

// ---------------- FUSED: MFMA GEMM tiles + per-chunk bucket histograms ----------------
// b < NCHUNK -> hist chunk b; else gemm tile g = b - NCHUNK
__global__ __launch_bounds__(256) void gemm_hist_k(
    const ushort* __restrict__ xb, const ushort* __restrict__ Wt,
    const float* __restrict__ bsrc, const float* __restrict__ bdst,
    __half* __restrict__ fsfd,
    const int* __restrict__ dst, int* __restrict__ chunk_hist)
{
    __shared__ ushort As[128 * 128];
    __shared__ ushort Bs[64 * 128];
    __shared__ int hist[NBKT];
    const int b = blockIdx.x;
    const int tid = threadIdx.x;

    if (b < NCHUNK) {
        // ---- hist role: 98-bucket LDS histogram of this 4096-edge chunk ----
        const int e0 = b * CHUNK;
        for (int t = tid; t < NBKT; t += 256) hist[t] = 0;
        __syncthreads();
        #pragma unroll
        for (int k = 0; k < 16; ++k) {
            const int e = e0 + k * 256 + tid;
            if (e < NE) atomicAdd(&hist[dst[e] >> 9], 1);
        }
        __syncthreads();
        for (int t = tid; t < NBKT; t += 256)
            chunk_hist[b * NBKT + t] = hist[t];
        return;
    }

    // ---- gemm role ----
    const int g = b - NCHUNK;
    const int bm = (g >> 2) * 128;
    const int bn = (g & 3) * 64;

    for (int q = tid; q < 128 * 16; q += 256) {
        int r = q >> 4, c16 = q & 15;
        int row = bm + r;
        uint4 v = make_uint4(0u, 0u, 0u, 0u);
        if (row < NN) v = *(const uint4*)&xb[row * FIN + c16 * 8];
        int off = r * 256 + ((c16 * 16) ^ ((r & 7) << 4));
        *(uint4*)((char*)As + off) = v;
    }
    for (int q = tid; q < 64 * 16; q += 256) {
        int r = q >> 4, c16 = q & 15;
        uint4 v = *(const uint4*)&Wt[(bn + r) * FIN + c16 * 8];
        int off = r * 256 + ((c16 * 16) ^ ((r & 7) << 4));
        *(uint4*)((char*)Bs + off) = v;
    }
    __syncthreads();

    const int wid = tid >> 6, lane = tid & 63;
    const int wr = (wid >> 1) * 64, wc = (wid & 1) * 32;
    const int lrow = lane & 15;
    const int lk = (lane >> 4) * 16;

    f32x4 acc[4][2] = {};
    #pragma unroll
    for (int kk = 0; kk < 4; ++kk) {
        bf16x8 a[4], bb[2];
        #pragma unroll
        for (int m = 0; m < 4; ++m) {
            int r = wr + m * 16 + lrow;
            int off = r * 256 + ((kk * 64 + lk) ^ ((r & 7) << 4));
            a[m] = *(bf16x8*)((char*)As + off);
        }
        #pragma unroll
        for (int n = 0; n < 2; ++n) {
            int r = wc + n * 16 + lrow;
            int off = r * 256 + ((kk * 64 + lk) ^ ((r & 7) << 4));
            bb[n] = *(bf16x8*)((char*)Bs + off);
        }
        #pragma unroll
        for (int m = 0; m < 4; ++m)
            #pragma unroll
            for (int n = 0; n < 2; ++n)
                acc[m][n] = __builtin_amdgcn_mfma_f32_16x16x32_bf16(a[m], bb[n], acc[m][n], 0, 0, 0);
    }

    #pragma unroll
    for (int m = 0; m < 4; ++m) {
        #pragma unroll
        for (int n = 0; n < 2; ++n) {
            int gcol = bn + wc + n * 16 + (lane & 15);
            float bias = (gcol < 128) ? bsrc[gcol] : bdst[gcol - 128];
            #pragma unroll
            for (int r = 0; r < 4; ++r) {
                int grow = bm + wr + m * 16 + (lane >> 4) * 4 + r;
                if (grow < NN)
                    fsfd[(size_t)grow * 256 + gcol] = __float2half(acc[m][n][r] + bias);
            }
        }
    }
}

// ---------------- per-bucket scan over chunks: chunk_base + bucket totals ----------------
__global__ __launch_bounds__(256) void scan_chunks_k(
    const int* __restrict__ chunk_hist, int* __restrict__ chunk_base, int* __restrict__ btotal)
{
    __shared__ int sh[256];
    const int b = blockIdx.x, t = threadIdx.x;
    const int v = (t < NCHUNK) ? chunk_hist[t * NBKT + b] : 0;
    sh[t] = v;
    __syncthreads();
    for (int off = 1; off < 256; off <<= 1) {
        int add = (t >= off) ? sh[t - off] : 0;
        __syncthreads();
        sh[t] += add;
        __syncthreads();
    }
    if (t < NCHUNK) chunk_base[t * NBKT + b] = sh[t] - v;   // exclusive
    if (t == 255) btotal[b] = sh[255];
}

// ---------------- cross-bucket exclusive scan + attn->f16 ----------------
__global__ __launch_bounds__(256) void scan_buckets_k(
    const int* __restrict__ btotal, int* __restrict__ bkbase,
    const float* __restrict__ attn, __half* __restrict__ attn_h)
{
    __shared__ int sh[256];
    const int t = threadIdx.x;
    const int v = (t < NBKT) ? btotal[t] : 0;
    sh[t] = v;
    __syncthreads();
    for (int off = 1; off < 256; off <<= 1) {
        int add = (t >= off) ? sh[t - off] : 0;
        __syncthreads();
        sh[t] += add;
        __syncthreads();
    }
    if (t < NBKT) bkbase[t] = sh[t] - v;     // exclusive
    if (t == 0) bkbase[NBKT] = NE;
    if (t < FOUT) attn_h[t] = __float2half(attn[t]);
}

// ---------------- scatter: positions fully precomputed, NO global atomics ----------------
__global__ __launch_bounds__(256) void scatter_k(
    const int* __restrict__ dst, const int* __restrict__ src,
    const int* __restrict__ bkbase, const int* __restrict__ chunk_base,
    uint* __restrict__ ebuf)
{
    __shared__ int cur[NBKT];
    const int chunk = blockIdx.x;
    const int tid = threadIdx.x;
    for (int t = tid; t < NBKT; t += 256)
        cur[t] = bkbase[t] + chunk_base[chunk * NBKT + t];
    __syncthreads();
    const int e0 = chunk * CHUNK;
    #pragma unroll
    for (int k = 0; k < 16; ++k) {
        const int e = e0 + k * 256 + tid;
        if (e < NE) {
            const int d = dst[e];
            const int p = atomicAdd(&cur[d >> 9], 1);   // LDS atomic
            ebuf[p] = ((uint)d << 16) | (uint)src[e];
        }
    }
}

// ---------------- binB: per-bucket rowptr build (LDS) + coalesced nbr ----------------
__global__ __launch_bounds__(256) void binB_k(
    const uint* __restrict__ ebuf, const int* __restrict__ bkbase,
    int* __restrict__ rowptr, ushort* __restrict__ nbr)
{
    __shared__ int cnt_s[512];
    __shared__ int ps[256];
    __shared__ ushort buf[BCAP];
    const int b = blockIdx.x;
    const int tid = threadIdx.x;
    const int node0 = b << 9;
    const int nodes = (node0 + 512 < NN) ? 512 : (NN - node0);
    const int segbase = bkbase[b];
    const int segend  = bkbase[b + 1];
    const int seglen  = segend - segbase;

    cnt_s[tid] = 0;
    cnt_s[tid + 256] = 0;
    __syncthreads();
    for (int i = segbase + tid; i < segend; i += 256)
        atomicAdd(&cnt_s[(int)(ebuf[i] >> 16) - node0], 1);   // LDS atomic
    __syncthreads();

    // 512-wide exclusive prefix scan (2 elems/thread)
    const int c0 = cnt_s[2 * tid], c1 = cnt_s[2 * tid + 1];
    const int pair = c0 + c1;
    ps[tid] = pair;
    __syncthreads();
    for (int off = 1; off < 256; off <<= 1) {
        int add = (tid >= off) ? ps[tid - off] : 0;
        __syncthreads();
        ps[tid] += add;
        __syncthreads();
    }
    const int ex = ps[tid] - pair;
    __syncthreads();
    cnt_s[2 * tid] = ex;
    cnt_s[2 * tid + 1] = ex + c0;
    if (2 * tid < nodes)     rowptr[node0 + 2 * tid]     = segbase + ex;
    if (2 * tid + 1 < nodes) rowptr[node0 + 2 * tid + 1] = segbase + ex + c0;
    if (b == NBKT - 1 && tid == 0) rowptr[NN] = segend;
    __syncthreads();

    if (seglen <= BCAP) {
        for (int i = segbase + tid; i < segend; i += 256) {
            const uint e = ebuf[i];
            const int d = (int)(e >> 16) - node0;
            const int p = atomicAdd(&cnt_s[d], 1);
            buf[p] = (ushort)(e & 0xffffu);
        }
        __syncthreads();
        for (int i = tid; i < seglen; i += 256)
            nbr[segbase + i] = buf[i];
    } else {
        // correctness fallback: direct (uncoalesced) global writes
        for (int i = segbase + tid; i < segend; i += 256) {
            const uint e = ebuf[i];
            const int d = (int)(e >> 16) - node0;
            const int p = atomicAdd(&cnt_s[d], 1);
            nbr[segbase + p] = (ushort)(e & 0xffffu);
        }
    }
}

// ---------------- Fused per-node GAT kernel (packed f16 math) ----------------
// One wave per node. ql = lane&15 owns elems {8ql..8ql+7} (4 half2); quarter-waves
// process 4 edges concurrently. Head = ql>>2; score reduce = 2 quad-DPP adds.
__global__ __launch_bounds__(256) void gat_node_k(
    const __half* __restrict__ fsfd, const __half* __restrict__ attn_h,
    const int* __restrict__ rowptr, const ushort* __restrict__ nbr,
    float* __restrict__ out)
{
    const int node = blockIdx.x * 4 + (threadIdx.x >> 6);
    const int lane = threadIdx.x & 63;
    const int ql = lane & 15;
    const int q  = lane >> 4;

    const uint4 ufd = *(const uint4*)&fsfd[(size_t)node * 256 + 128 + 8 * ql];
    const __half2 fd0 = u2h(ufd.x), fd1 = u2h(ufd.y), fd2 = u2h(ufd.z), fd3 = u2h(ufd.w);
    const uint4 uav = *(const uint4*)&attn_h[8 * ql];
    const __half2 av0 = u2h(uav.x), av1 = u2h(uav.y), av2 = u2h(uav.z), av3 = u2h(uav.w);
    const __half2 k02 = __float2half2_rn(NEG);

    const int beg = rowptr[node];
    const int end = rowptr[node + 1];

    float den = 0.f;
    __half2 acc0 = u2h(0), acc1 = u2h(0), acc2 = u2h(0), acc3 = u2h(0);

    for (int i = beg; i < end; i += 8) {
        #pragma unroll
        for (int j = 0; j < 2; ++j) {
            const int idx = i + 4 * j + q;
            const bool valid = idx < end;
            const int s = nbr[valid ? idx : end - 1];
            const uint4 u = *(const uint4*)&fsfd[(size_t)s * 256 + 8 * ql];
            const __half2 f0 = u2h(u.x), f1 = u2h(u.y), f2 = u2h(u.z), f3 = u2h(u.w);
            __half2 v0 = __hadd2(f0, fd0), v1 = __hadd2(f1, fd1);
            __half2 v2 = __hadd2(f2, fd2), v3 = __hadd2(f3, fd3);
            v0 = hmax2(v0, __hmul2(v0, k02));
            v1 = hmax2(v1, __hmul2(v1, k02));
            v2 = hmax2(v2, __hmul2(v2, k02));
            v3 = hmax2(v3, __hmul2(v3, k02));
            __half2 sch = __hmul2(v0, av0);
            sch = __hfma2(v1, av1, sch);
            sch = __hfma2(v2, av2, sch);
            sch = __hfma2(v3, av3, sch);
            float sc = __low2float(sch) + __high2float(sch);
            sc = dpp_add<DPP_QUAD_XOR1>(sc);
            sc = dpp_add<DPP_QUAD_XOR2>(sc);
            float ex = __expf(sc);
            ex = valid ? ex : 0.f;
            den += ex;
            const __half2 exh = __float2half2_rn(ex);
            acc0 = __hfma2(exh, f0, acc0);
            acc1 = __hfma2(exh, f1, acc1);
            acc2 = __hfma2(exh, f2, acc2);
            acc3 = __hfma2(exh, f3, acc3);
        }
    }

    den += __shfl_xor(den, 16, 64);
    den += __shfl_xor(den, 32, 64);
    uint ua0 = h2u(acc0), ua1 = h2u(acc1), ua2 = h2u(acc2), ua3 = h2u(acc3);
    ua0 = h2u(__hadd2(u2h(ua0), u2h((uint)__shfl_xor((int)ua0, 16, 64))));
    ua1 = h2u(__hadd2(u2h(ua1), u2h((uint)__shfl_xor((int)ua1, 16, 64))));
    ua2 = h2u(__hadd2(u2h(ua2), u2h((uint)__shfl_xor((int)ua2, 16, 64))));
    ua3 = h2u(__hadd2(u2h(ua3), u2h((uint)__shfl_xor((int)ua3, 16, 64))));
    ua0 = h2u(__hadd2(u2h(ua0), u2h((uint)__shfl_xor((int)ua0, 32, 64))));
    ua1 = h2u(__hadd2(u2h(ua1), u2h((uint)__shfl_xor((int)ua1, 32, 64))));
    ua2 = h2u(__hadd2(u2h(ua2), u2h((uint)__shfl_xor((int)ua2, 32, 64))));
    ua3 = h2u(__hadd2(u2h(ua3), u2h((uint)__shfl_xor((int)ua3, 32, 64))));

    if (q == 0) {
        const float inv = (den > 0.f) ? 1.f / den : 0.f;
        float4 o0, o1;
        o0.x = fmaxf(__low2float(u2h(ua0))  * inv, 0.f);
        o0.y = fmaxf(__high2float(u2h(ua0)) * inv, 0.f);
        o0.z = fmaxf(__low2float(u2h(ua1))  * inv, 0.f);
        o0.w = fmaxf(__high2float(u2h(ua1)) * inv, 0.f);
        o1.x = fmaxf(__low2float(u2h(ua2))  * inv, 0.f);
        o1.y = fmaxf(__high2float(u2h(ua2)) * inv, 0.f);
        o1.z = fmaxf(__low2float(u2h(ua3))  * inv, 0.f);
        o1.w = fmaxf(__high2float(u2h(ua3)) * inv, 0.f);
        *(float4*)&out[(size_t)node * FOUT + 8 * ql] = o0;
        *(float4*)&out[(size_t)node * FOUT + 8 * ql + 4] = o1;
    }
}

extern "C" void kernel_launch(void* const* d_in, const int* in_sizes, int n_in,
                              void* d_out, int out_size, void* d_ws, size_t ws_size,
                              hipStream_t stream)
{
    const float* x    = (const float*)d_in[0];
    const int*   src  = (const int*)d_in[1];
    const int*   dst  = (const int*)d_in[2];
    const float* Wsrc = (const float*)d_in[3];
    const float* bsrc = (const float*)d_in[4];
    const float* Wdst = (const float*)d_in[5];
    const float* bdst = (const float*)d_in[6];
    const float* attn = (const float*)d_in[7];
    float* out = (float*)d_out;

    ushort* xb      = (ushort*)d_ws;                      // NN*128 bf16
    ushort* Wt      = xb + (size_t)NN * FIN;              // 256*128 bf16
    __half* fsfd    = (__half*)(Wt + 256 * FIN);          // NN*256 f16
    int* chunk_hist = (int*)(fsfd + (size_t)NN * 256);    // NCHUNK*NBKT
    int* chunk_base = chunk_hist + NCHUNK * NBKT;         // NCHUNK*NBKT
    int* btotal     = chunk_base + NCHUNK * NBKT;         // NBKT
    int* bkbase     = btotal + NBKT;                      // NBKT+1
    int* rowptr     = bkbase + NBKT + 1;                  // NN+1
    uint* ebuf      = (uint*)(rowptr + NN + 1);           // NE packed (d<<16)|s
    ushort* nbr     = (ushort*)(ebuf + NE);               // NE u16
    __half* attn_h  = (__half*)(nbr + NE);                // 128 f16

    conv_all_k<<<NB_EDGE + NB_W, 256, 0, stream>>>(x, xb, Wsrc, Wdst, Wt);
    gemm_hist_k<<<NCHUNK + N_GEMM, 256, 0, stream>>>(xb, Wt, bsrc, bdst, fsfd,
                                                     dst, chunk_hist);
    scan_chunks_k<<<NBKT, 256, 0, stream>>>(chunk_hist, chunk_base, btotal);
    scan_buckets_k<<<1, 256, 0, stream>>>(btotal, bkbase, attn, attn_h);
    scatter_k<<<NCHUNK, 256, 0, stream>>>(dst, src, bkbase, chunk_base, ebuf);
    binB_k<<<NBKT, 256, 0, stream>>>(ebuf, bkbase, rowptr, nbr);
    gat_node_k<<<(NN + 3) / 4, 256, 0, stream>>>(fsfd, attn_h, rowptr, nbr, out);
}

// Round 12
// 98.484 us; speedup vs baseline: 1.3297x; 1.0433x over previous
//
#include <hip/hip_runtime.h>
#include <hip/hip_fp16.h>

#define NN 50000
#define NE 800000
#define FIN 128
#define NH 4
#define HD 32
#define FOUT 128   // NH*HD
#define NEG 0.2f
#define NB_W    ((256 * FIN + 255) / 256) // 128
#define N_GEMM  (391 * 4)            // 1564 gemm tiles
#define NBKT    98                   // dst>>9 buckets (512 nodes each)
#define CHUNK   4096                 // edges per hist/scatter chunk
#define NCHUNK  ((NE + CHUNK - 1) / CHUNK)  // 196
#define GB_GRID (NCHUNK * 9)         // 1764: b%9==0 -> scatter, else gemm
#define BCAP    12288                // binB LDS segment capacity (mean 8163, max ~8600)

typedef __attribute__((ext_vector_type(8))) short bf16x8;
typedef __attribute__((ext_vector_type(4))) float f32x4;

__device__ __forceinline__ uint f2bf_u(float f) {
    uint u = __float_as_uint(f);
    u += 0x7FFF + ((u >> 16) & 1);   // round-to-nearest-even
    return u >> 16;
}
__device__ __forceinline__ ushort f2bf(float f) { return (ushort)f2bf_u(f); }

template<int CTRL>
__device__ __forceinline__ float dpp_add(float x) {
    int y = __builtin_amdgcn_update_dpp(0, __float_as_int(x), CTRL, 0xF, 0xF, false);
    return x + __int_as_float(y);
}
#define DPP_QUAD_XOR1 0xB1   // quad_perm [1,0,3,2]
#define DPP_QUAD_XOR2 0x4E   // quad_perm [2,3,0,1]

__device__ __forceinline__ __half2 u2h(uint u) { return __builtin_bit_cast(__half2, u); }
__device__ __forceinline__ uint h2u(__half2 h) { return __builtin_bit_cast(uint, h); }

// ROCm 7.2 hip_fp16.h lacks __hmax2 — emit v_pk_max_f16 directly
__device__ __forceinline__ __half2 hmax2(__half2 a, __half2 b) {
    uint r, ua = h2u(a), ub = h2u(b);
    asm("v_pk_max_f16 %0, %1, %2" : "=v"(r) : "v"(ua), "v"(ub));
    return u2h(r);
}

// ---------------- hist chunks + Wt conversion (one launch, independent roles) ----------------
__global__ __launch_bounds__(256) void hist_wt_k(
    const int* __restrict__ dst, int* __restrict__ chunk_hist,
    const float* __restrict__ Wsrc, const float* __restrict__ Wdst,
    ushort* __restrict__ Wt)
{
    __shared__ int hist[NBKT];
    const int b = blockIdx.x;
    const int tid = threadIdx.x;
    if (b < NCHUNK) {
        const int e0 = b * CHUNK;
        for (int t = tid; t < NBKT; t += 256) hist[t] = 0;
        __syncthreads();
        #pragma unroll
        for (int k = 0; k < 16; ++k) {
            const int e = e0 + k * 256 + tid;
            if (e < NE) atomicAdd(&hist[dst[e] >> 9], 1);
        }
        __syncthreads();
        for (int t = tid; t < NBKT; t += 256)
            chunk_hist[b * NBKT + t] = hist[t];
    } else {
        int t = (b - NCHUNK) * 256 + tid;
        if (t >= 256 * FIN) return;
        int n = t >> 7, k = t & 127;
        float v = (n < 128) ? Wsrc[k * 128 + n] : Wdst[k * 128 + (n - 128)];
        Wt[t] = f2bf(v);
    }
}

// ---------------- per-bucket scan over chunks ----------------
__global__ __launch_bounds__(256) void scan_chunks_k(
    const int* __restrict__ chunk_hist, int* __restrict__ chunk_base, int* __restrict__ btotal)
{
    __shared__ int sh[256];
    const int b = blockIdx.x, t = threadIdx.x;
    const int v = (t < NCHUNK) ? chunk_hist[t * NBKT + b] : 0;
    sh[t] = v;
    __syncthreads();
    for (int off = 1; off < 256; off <<= 1) {
        int add = (t >= off) ? sh[t - off] : 0;
        __syncthreads();
        sh[t] += add;
        __syncthreads();
    }
    if (t < NCHUNK) chunk_base[t * NBKT + b] = sh[t] - v;   // exclusive
    if (t == 255) btotal[b] = sh[255];
}

// ---------------- cross-bucket exclusive scan + attn->f16 ----------------
__global__ __launch_bounds__(256) void scan_buckets_k(
    const int* __restrict__ btotal, int* __restrict__ bkbase,
    const float* __restrict__ attn, __half* __restrict__ attn_h)
{
    __shared__ int sh[256];
    const int t = threadIdx.x;
    const int v = (t < NBKT) ? btotal[t] : 0;
    sh[t] = v;
    __syncthreads();
    for (int off = 1; off < 256; off <<= 1) {
        int add = (t >= off) ? sh[t - off] : 0;
        __syncthreads();
        sh[t] += add;
        __syncthreads();
    }
    if (t < NBKT) bkbase[t] = sh[t] - v;     // exclusive
    if (t == 0) bkbase[NBKT] = NE;
    if (t < FOUT) attn_h[t] = __float2half(attn[t]);
}

// ---------------- FUSED: MFMA GEMM (f32 x, inline bf16 cvt) + atomic-free scatter ----------------
// b % 9 == 0 -> scatter chunk b/9 (196); else gemm tile g = b - b/9 - 1 (1564 + guard)
__global__ __launch_bounds__(256) void gemm_scatter_k(
    const float* __restrict__ x, const ushort* __restrict__ Wt,
    const float* __restrict__ bsrc, const float* __restrict__ bdst,
    __half* __restrict__ fsfd,
    const int* __restrict__ dst, const int* __restrict__ src,
    const int* __restrict__ bkbase, const int* __restrict__ chunk_base,
    uint* __restrict__ ebuf)
{
    __shared__ ushort As[128 * 128];
    __shared__ ushort Bs[64 * 128];
    __shared__ int cur[NBKT];
    const int b = blockIdx.x;
    const int tid = threadIdx.x;

    if (b % 9 == 0) {
        // ---- scatter role: positions precomputed, LDS cursors only ----
        const int chunk = b / 9;
        for (int t = tid; t < NBKT; t += 256)
            cur[t] = bkbase[t] + chunk_base[chunk * NBKT + t];
        __syncthreads();
        const int e0 = chunk * CHUNK;
        #pragma unroll
        for (int k = 0; k < 16; ++k) {
            const int e = e0 + k * 256 + tid;
            if (e < NE) {
                const int d = dst[e];
                const int p = atomicAdd(&cur[d >> 9], 1);   // LDS atomic
                ebuf[p] = ((uint)d << 16) | (uint)src[e];
            }
        }
        return;
    }

    // ---- gemm role ----
    const int g = b - b / 9 - 1;
    if (g >= N_GEMM) return;
    const int bm = (g >> 2) * 128;
    const int bn = (g & 3) * 64;

    // A tile: read f32 x, convert to bf16 in-register, swizzled LDS write
    for (int q = tid; q < 128 * 16; q += 256) {
        int r = q >> 4, c16 = q & 15;
        int row = bm + r;
        uint4 o = make_uint4(0u, 0u, 0u, 0u);
        if (row < NN) {
            const float4 a = *(const float4*)&x[(size_t)row * FIN + c16 * 8];
            const float4 c = *(const float4*)&x[(size_t)row * FIN + c16 * 8 + 4];
            o.x = f2bf_u(a.x) | (f2bf_u(a.y) << 16);
            o.y = f2bf_u(a.z) | (f2bf_u(a.w) << 16);
            o.z = f2bf_u(c.x) | (f2bf_u(c.y) << 16);
            o.w = f2bf_u(c.z) | (f2bf_u(c.w) << 16);
        }
        int off = r * 256 + ((c16 * 16) ^ ((r & 7) << 4));
        *(uint4*)((char*)As + off) = o;
    }
    for (int q = tid; q < 64 * 16; q += 256) {
        int r = q >> 4, c16 = q & 15;
        uint4 v = *(const uint4*)&Wt[(bn + r) * FIN + c16 * 8];
        int off = r * 256 + ((c16 * 16) ^ ((r & 7) << 4));
        *(uint4*)((char*)Bs + off) = v;
    }
    __syncthreads();

    const int wid = tid >> 6, lane = tid & 63;
    const int wr = (wid >> 1) * 64, wc = (wid & 1) * 32;
    const int lrow = lane & 15;
    const int lk = (lane >> 4) * 16;

    f32x4 acc[4][2] = {};
    #pragma unroll
    for (int kk = 0; kk < 4; ++kk) {
        bf16x8 a[4], bb[2];
        #pragma unroll
        for (int m = 0; m < 4; ++m) {
            int r = wr + m * 16 + lrow;
            int off = r * 256 + ((kk * 64 + lk) ^ ((r & 7) << 4));
            a[m] = *(bf16x8*)((char*)As + off);
        }
        #pragma unroll
        for (int n = 0; n < 2; ++n) {
            int r = wc + n * 16 + lrow;
            int off = r * 256 + ((kk * 64 + lk) ^ ((r & 7) << 4));
            bb[n] = *(bf16x8*)((char*)Bs + off);
        }
        #pragma unroll
        for (int m = 0; m < 4; ++m)
            #pragma unroll
            for (int n = 0; n < 2; ++n)
                acc[m][n] = __builtin_amdgcn_mfma_f32_16x16x32_bf16(a[m], bb[n], acc[m][n], 0, 0, 0);
    }

    #pragma unroll
    for (int m = 0; m < 4; ++m) {
        #pragma unroll
        for (int n = 0; n < 2; ++n) {
            int gcol = bn + wc + n * 16 + (lane & 15);
            float bias = (gcol < 128) ? bsrc[gcol] : bdst[gcol - 128];
            #pragma unroll
            for (int r = 0; r < 4; ++r) {
                int grow = bm + wr + m * 16 + (lane >> 4) * 4 + r;
                if (grow < NN)
                    fsfd[(size_t)grow * 256 + gcol] = __float2half(acc[m][n][r] + bias);
            }
        }
    }
}

// ---------------- binB: per-bucket rowptr build (LDS) + coalesced nbr ----------------
__global__ __launch_bounds__(256) void binB_k(
    const uint* __restrict__ ebuf, const int* __restrict__ bkbase,
    int* __restrict__ rowptr, ushort* __restrict__ nbr)
{
    __shared__ int cnt_s[512];
    __shared__ int ps[256];
    __shared__ ushort buf[BCAP];
    const int b = blockIdx.x;
    const int tid = threadIdx.x;
    const int node0 = b << 9;
    const int nodes = (node0 + 512 < NN) ? 512 : (NN - node0);
    const int segbase = bkbase[b];
    const int segend  = bkbase[b + 1];
    const int seglen  = segend - segbase;

    cnt_s[tid] = 0;
    cnt_s[tid + 256] = 0;
    __syncthreads();
    for (int i = segbase + tid; i < segend; i += 256)
        atomicAdd(&cnt_s[(int)(ebuf[i] >> 16) - node0], 1);   // LDS atomic
    __syncthreads();

    // 512-wide exclusive prefix scan (2 elems/thread)
    const int c0 = cnt_s[2 * tid], c1 = cnt_s[2 * tid + 1];
    const int pair = c0 + c1;
    ps[tid] = pair;
    __syncthreads();
    for (int off = 1; off < 256; off <<= 1) {
        int add = (tid >= off) ? ps[tid - off] : 0;
        __syncthreads();
        ps[tid] += add;
        __syncthreads();
    }
    const int ex = ps[tid] - pair;
    __syncthreads();
    cnt_s[2 * tid] = ex;
    cnt_s[2 * tid + 1] = ex + c0;
    if (2 * tid < nodes)     rowptr[node0 + 2 * tid]     = segbase + ex;
    if (2 * tid + 1 < nodes) rowptr[node0 + 2 * tid + 1] = segbase + ex + c0;
    if (b == NBKT - 1 && tid == 0) rowptr[NN] = segend;
    __syncthreads();

    if (seglen <= BCAP) {
        for (int i = segbase + tid; i < segend; i += 256) {
            const uint e = ebuf[i];
            const int d = (int)(e >> 16) - node0;
            const int p = atomicAdd(&cnt_s[d], 1);
            buf[p] = (ushort)(e & 0xffffu);
        }
        __syncthreads();
        for (int i = tid; i < seglen; i += 256)
            nbr[segbase + i] = buf[i];
    } else {
        // correctness fallback: direct (uncoalesced) global writes
        for (int i = segbase + tid; i < segend; i += 256) {
            const uint e = ebuf[i];
            const int d = (int)(e >> 16) - node0;
            const int p = atomicAdd(&cnt_s[d], 1);
            nbr[segbase + p] = (ushort)(e & 0xffffu);
        }
    }
}

// ---------------- Fused per-node GAT kernel (packed f16, 4 gathers in flight) ----------------
// One wave per node. ql = lane&15 owns elems {8ql..8ql+7} (4 half2); quarter-waves
// process 4 edges concurrently; i-step 16 keeps 4 row-gathers in flight per quarter.
__global__ __launch_bounds__(256) void gat_node_k(
    const __half* __restrict__ fsfd, const __half* __restrict__ attn_h,
    const int* __restrict__ rowptr, const ushort* __restrict__ nbr,
    float* __restrict__ out)
{
    const int node = blockIdx.x * 4 + (threadIdx.x >> 6);
    const int lane = threadIdx.x & 63;
    const int ql = lane & 15;
    const int q  = lane >> 4;

    const uint4 ufd = *(const uint4*)&fsfd[(size_t)node * 256 + 128 + 8 * ql];
    const __half2 fd0 = u2h(ufd.x), fd1 = u2h(ufd.y), fd2 = u2h(ufd.z), fd3 = u2h(ufd.w);
    const uint4 uav = *(const uint4*)&attn_h[8 * ql];
    const __half2 av0 = u2h(uav.x), av1 = u2h(uav.y), av2 = u2h(uav.z), av3 = u2h(uav.w);
    const __half2 k02 = __float2half2_rn(NEG);

    const int beg = rowptr[node];
    const int end = rowptr[node + 1];

    float den = 0.f;
    __half2 acc0 = u2h(0), acc1 = u2h(0), acc2 = u2h(0), acc3 = u2h(0);

    for (int i = beg; i < end; i += 16) {
        // 4 independent gathers issued up-front (compiler hoists the loads)
        #pragma unroll
        for (int j = 0; j < 4; ++j) {
            const int idx = i + 4 * j + q;
            const bool valid = idx < end;
            const int s = nbr[valid ? idx : end - 1];
            const uint4 u = *(const uint4*)&fsfd[(size_t)s * 256 + 8 * ql];
            const __half2 f0 = u2h(u.x), f1 = u2h(u.y), f2 = u2h(u.z), f3 = u2h(u.w);
            __half2 v0 = __hadd2(f0, fd0), v1 = __hadd2(f1, fd1);
            __half2 v2 = __hadd2(f2, fd2), v3 = __hadd2(f3, fd3);
            v0 = hmax2(v0, __hmul2(v0, k02));
            v1 = hmax2(v1, __hmul2(v1, k02));
            v2 = hmax2(v2, __hmul2(v2, k02));
            v3 = hmax2(v3, __hmul2(v3, k02));
            __half2 sch = __hmul2(v0, av0);
            sch = __hfma2(v1, av1, sch);
            sch = __hfma2(v2, av2, sch);
            sch = __hfma2(v3, av3, sch);
            float sc = __low2float(sch) + __high2float(sch);
            sc = dpp_add<DPP_QUAD_XOR1>(sc);
            sc = dpp_add<DPP_QUAD_XOR2>(sc);
            float ex = __expf(sc);
            ex = valid ? ex : 0.f;
            den += ex;
            const __half2 exh = __float2half2_rn(ex);
            acc0 = __hfma2(exh, f0, acc0);
            acc1 = __hfma2(exh, f1, acc1);
            acc2 = __hfma2(exh, f2, acc2);
            acc3 = __hfma2(exh, f3, acc3);
        }
    }

    den += __shfl_xor(den, 16, 64);
    den += __shfl_xor(den, 32, 64);
    uint ua0 = h2u(acc0), ua1 = h2u(acc1), ua2 = h2u(acc2), ua3 = h2u(acc3);
    ua0 = h2u(__hadd2(u2h(ua0), u2h((uint)__shfl_xor((int)ua0, 16, 64))));
    ua1 = h2u(__hadd2(u2h(ua1), u2h((uint)__shfl_xor((int)ua1, 16, 64))));
    ua2 = h2u(__hadd2(u2h(ua2), u2h((uint)__shfl_xor((int)ua2, 16, 64))));
    ua3 = h2u(__hadd2(u2h(ua3), u2h((uint)__shfl_xor((int)ua3, 16, 64))));
    ua0 = h2u(__hadd2(u2h(ua0), u2h((uint)__shfl_xor((int)ua0, 32, 64))));
    ua1 = h2u(__hadd2(u2h(ua1), u2h((uint)__shfl_xor((int)ua1, 32, 64))));
    ua2 = h2u(__hadd2(u2h(ua2), u2h((uint)__shfl_xor((int)ua2, 32, 64))));
    ua3 = h2u(__hadd2(u2h(ua3), u2h((uint)__shfl_xor((int)ua3, 32, 64))));

    if (q == 0) {
        const float inv = (den > 0.f) ? 1.f / den : 0.f;
        float4 o0, o1;
        o0.x = fmaxf(__low2float(u2h(ua0))  * inv, 0.f);
        o0.y = fmaxf(__high2float(u2h(ua0)) * inv, 0.f);
        o0.z = fmaxf(__low2float(u2h(ua1))  * inv, 0.f);
        o0.w = fmaxf(__high2float(u2h(ua1)) * inv, 0.f);
        o1.x = fmaxf(__low2float(u2h(ua2))  * inv, 0.f);
        o1.y = fmaxf(__high2float(u2h(ua2)) * inv, 0.f);
        o1.z = fmaxf(__low2float(u2h(ua3))  * inv, 0.f);
        o1.w = fmaxf(__high2float(u2h(ua3)) * inv, 0.f);
        *(float4*)&out[(size_t)node * FOUT + 8 * ql] = o0;
        *(float4*)&out[(size_t)node * FOUT + 8 * ql + 4] = o1;
    }
}

extern "C" void kernel_launch(void* const* d_in, const int* in_sizes, int n_in,
                              void* d_out, int out_size, void* d_ws, size_t ws_size,
                              hipStream_t stream)
{
    const float* x    = (const float*)d_in[0];
    const int*   src  = (const int*)d_in[1];
    const int*   dst  = (const int*)d_in[2];
    const float* Wsrc = (const float*)d_in[3];
    const float* bsrc = (const float*)d_in[4];
    const float* Wdst = (const float*)d_in[5];
    const float* bdst = (const float*)d_in[6];
    const float* attn = (const float*)d_in[7];
    float* out = (float*)d_out;

    ushort* Wt      = (ushort*)d_ws;                      // 256*128 bf16
    __half* fsfd    = (__half*)(Wt + 256 * FIN);          // NN*256 f16
    int* chunk_hist = (int*)(fsfd + (size_t)NN * 256);    // NCHUNK*NBKT
    int* chunk_base = chunk_hist + NCHUNK * NBKT;         // NCHUNK*NBKT
    int* btotal     = chunk_base + NCHUNK * NBKT;         // NBKT
    int* bkbase     = btotal + NBKT;                      // NBKT+1
    int* rowptr     = bkbase + NBKT + 1;                  // NN+1
    uint* ebuf      = (uint*)(rowptr + NN + 1);           // NE packed (d<<16)|s
    ushort* nbr     = (ushort*)(ebuf + NE);               // NE u16
    __half* attn_h  = (__half*)(nbr + NE);                // 128 f16

    hist_wt_k<<<NCHUNK + NB_W, 256, 0, stream>>>(dst, chunk_hist, Wsrc, Wdst, Wt);
    scan_chunks_k<<<NBKT, 256, 0, stream>>>(chunk_hist, chunk_base, btotal);
    scan_buckets_k<<<1, 256, 0, stream>>>(btotal, bkbase, attn, attn_h);
    gemm_scatter_k<<<GB_GRID, 256, 0, stream>>>(x, Wt, bsrc, bdst, fsfd,
                                                dst, src, bkbase, chunk_base, ebuf);
    binB_k<<<NBKT, 256, 0, stream>>>(ebuf, bkbase, rowptr, nbr);
    gat_node_k<<<(NN + 3) / 4, 256, 0, stream>>>(fsfd, attn_h, rowptr, nbr, out);
}